// Round 2
// baseline (70976.257 us; speedup 1.0000x reference)
//
#include <hip/hip_runtime.h>
#include <math.h>

#define T_STEPS 1000
#define KK 32
#define D0 128
#define D1 256
#define D2 512
#define IMGH 105
#define IMGW 105
#define NPIX (IMGH*IMGW)
#define DTTAU 0.01f

// ---- workspace float offsets ----
#define OFF_M0   0          // 128*128
#define OFF_S0   16384      // 1001*128 states (S[t] = state at START of step t)
#define OFF_S1   144512     // 1001*256
#define OFF_S2   400768     // 1001*512
#define OFF_AL1  913280     // 1000*32  alpha1(t)
#define OFF_AL2  945280     // 1000*32  alpha2(t)
#define OFF_AAX0 977280     // 1000*128 per-step accumulators (zeroed by setup)
#define OFF_AAX1 1105280    // 1000*256
#define OFF_AAX2 1361280    // 1000*512
#define OFF_U1A  1873280    // 1000*256
#define OFF_U2A  2129280    // 1000*512
#define OFF_PXYP 2641280    // 1000*3 (pen_in_y, pen_in_x, pdlp)
#define OFF_PENS 2644280    // 2 pen state
#define OFF_CTR  2644282    // 1000 ints (step counters)
#define ZERO_BASE OFF_AAX0
#define ZERO_LEN  1664000

// ---- output float offsets (reference return order, each stacked over T) ----
#define OA0  0          // (1000,32)  alphas[0] = z1 broadcast
#define OA1  32000      // (1000,32)
#define OA2  64000      // (1000,32)
#define OU0  96000      // (1000,128) zeros
#define OU1  224000     // (1000,256)
#define OU2  480000     // (1000,512)
#define OX0  992000     // (1000,128)
#define OX1  1120000    // (1000,256)
#define OX2  1376000    // (1000,512)
#define OPEN 1888000    // (1000,2)
#define OPXY 1890000    // (1000,105,105)
#define OPDLP 12915000  // (1000,)

#define NBLK 512
#define NTHR 256
// rows: A2: 32*512=16384 | A1: 32*256=8192 | M0: 128 | u2: 512 | u1: 256
#define NROWS 25472

__device__ __forceinline__ float waveReduceSum(float v) {
    for (int m = 32; m >= 1; m >>= 1) v += __shfl_xor(v, m, 64);
    return v;
}

// ---------------- setup: zero accumulators/counters, init states, pen0, alpha(0) ----------------
__global__ __launch_bounds__(NTHR) void setup_kernel(
    const void* __restrict__ dataRaw, const float* __restrict__ z1, const float* __restrict__ z2,
    const float* __restrict__ Wa0, const float* __restrict__ Wa1,
    const float* __restrict__ ba0, const float* __restrict__ ba1,
    float* __restrict__ ws, float* __restrict__ out)
{
    size_t gid = (size_t)blockIdx.x * blockDim.x + threadIdx.x;
    size_t nthr = (size_t)gridDim.x * blockDim.x;
    for (size_t i = gid; i < ZERO_LEN; i += nthr) ws[ZERO_BASE + i] = 0.f;
    int* ctr = (int*)(ws + OFF_CTR);
    for (size_t i = gid; i < T_STEPS; i += nthr) ctr[i] = 0;

    if (blockIdx.x != 0) return;
    int tid = threadIdx.x;

    // initial states: x0 = z2, x1 = 0, x2 = 0
    if (tid < D0) (ws + OFF_S0)[tid] = z2[tid];
    for (int i = tid; i < D1; i += NTHR) (ws + OFF_S1)[i] = 0.f;
    for (int i = tid; i < D2; i += NTHR) (ws + OFF_S2)[i] = 0.f;

    // pen0 = argwhere(data)[0]; robust to bool stored as uint8, int32, or float32
    __shared__ int sMin;
    if (tid == 0) sMin = 0x7fffffff;
    __syncthreads();
    const unsigned char* db = (const unsigned char*)dataRaw;
    for (int i = tid; i < NPIX; i += NTHR) if (db[i]) atomicMin(&sMin, i);
    __syncthreads();
    if (sMin == 0x7fffffff) {
        const int* di = (const int*)dataRaw;
        for (int i = tid; i < NPIX; i += NTHR) if (di[i] != 0) atomicMin(&sMin, i);
    }
    __syncthreads();
    if (tid == 0) {
        int idx = (sMin == 0x7fffffff) ? 0 : sMin;
        (ws + OFF_PENS)[0] = (float)(idx / IMGW);
        (ws + OFF_PENS)[1] = (float)(idx % IMGW);
    }

    // alpha1(0) = softmax(Wa0 @ z2 + ba0); alpha2(0) = softmax(ba1) (x1 starts at 0)
    if (tid < 64) {
        int lane = tid;
        float pre;
        if (lane < 32) {
            float s = 0.f;
            for (int j = 0; j < D0; j++) s += Wa0[lane * D0 + j] * z2[j];
            pre = s + ba0[lane];
        } else {
            pre = ba1[lane - 32];
        }
        float m = pre;
        for (int msk = 16; msk >= 1; msk >>= 1) m = fmaxf(m, __shfl_xor(m, msk, 64));
        float e = expf(pre - m);
        float ssum = e;
        for (int msk = 16; msk >= 1; msk >>= 1) ssum += __shfl_xor(ssum, msk, 64);
        float al = e / ssum;
        if (lane < 32) { (ws + OFF_AL1)[lane] = al; out[OA1 + lane] = al; }
        else           { (ws + OFF_AL2)[lane - 32] = al; out[OA2 + lane - 32] = al; }
    }
}

// ---------------- M0 = sum_k z1[k] * A0[k] ----------------
__global__ __launch_bounds__(NTHR) void m0_kernel(
    const float* __restrict__ z1, const float* __restrict__ A0, float* __restrict__ ws)
{
    int idx = blockIdx.x * NTHR + threadIdx.x;
    if (idx < D0 * D0) {
        float s = 0.f;
        for (int k = 0; k < KK; k++) s += z1[k] * A0[(size_t)k * D0 * D0 + idx];
        ws[OFF_M0 + idx] = s;
    }
}

// ---------------- trivial outputs: alpha0 broadcast, u0 zeros ----------------
__global__ __launch_bounds__(NTHR) void fill_kernel(const float* __restrict__ z1, float* __restrict__ out)
{
    size_t gid = (size_t)blockIdx.x * blockDim.x + threadIdx.x;
    size_t nthr = (size_t)gridDim.x * blockDim.x;
    for (size_t i = gid; i < 32000; i += nthr) out[OA0 + i] = z1[i & 31];
    for (size_t i = gid; i < 128000; i += nthr) out[OU0 + i] = 0.f;
}

// ---------------- one recurrence step ----------------
__global__ __launch_bounds__(NTHR) void step_kernel(
    int t,
    const float* __restrict__ A1, const float* __restrict__ A2,
    const float* __restrict__ Wu0, const float* __restrict__ Wu1,
    const float* __restrict__ Wa0, const float* __restrict__ Wa1,
    const float* __restrict__ ba0, const float* __restrict__ ba1,
    const float* __restrict__ Wp, const float* __restrict__ bp,
    const float* __restrict__ gam,
    float* __restrict__ ws, float* __restrict__ out)
{
    const float* s0 = ws + OFF_S0 + (size_t)t * D0;
    const float* s1 = ws + OFF_S1 + (size_t)t * D1;
    const float* s2 = ws + OFF_S2 + (size_t)t * D2;
    const float* al1 = ws + OFF_AL1 + (size_t)t * KK;
    const float* al2 = ws + OFF_AL2 + (size_t)t * KK;
    float* aax0 = ws + OFF_AAX0 + (size_t)t * D0;
    float* aax1 = ws + OFF_AAX1 + (size_t)t * D1;
    float* aax2 = ws + OFF_AAX2 + (size_t)t * D2;
    float* u1a  = ws + OFF_U1A  + (size_t)t * D1;
    float* u2a  = ws + OFF_U2A  + (size_t)t * D2;

    int tid = threadIdx.x;
    int lane = tid & 63;
    int wv = (blockIdx.x * NTHR + tid) >> 6;
    const int nwv = (NBLK * NTHR) >> 6;

    const float4* xv2 = (const float4*)s2;
    const float4* xv1 = (const float4*)s1;
    const float4* xv0 = (const float4*)s0;

    for (int r = wv; r < NROWS; r += nwv) {
        float p = 0.f;
        if (r < 16384) {                       // layer2 A rows: k=r>>9, i=r&511
            const float4* row = (const float4*)(A2 + ((size_t)r << 9));
            float4 a0v = row[lane], b0 = xv2[lane];
            float4 a1v = row[lane + 64], b1 = xv2[lane + 64];
            p = a0v.x*b0.x + a0v.y*b0.y + a0v.z*b0.z + a0v.w*b0.w
              + a1v.x*b1.x + a1v.y*b1.y + a1v.z*b1.z + a1v.w*b1.w;
            p = waveReduceSum(p);
            if (lane == 0) atomicAdd(&aax2[r & 511], al2[r >> 9] * p);
        } else if (r < 24576) {                // layer1 A rows
            int r2 = r - 16384;
            const float4* row = (const float4*)(A1 + ((size_t)r2 << 8));
            float4 a = row[lane], b = xv1[lane];
            p = a.x*b.x + a.y*b.y + a.z*b.z + a.w*b.w;
            p = waveReduceSum(p);
            if (lane == 0) atomicAdd(&aax1[r2 & 255], al1[r2 >> 8] * p);
        } else if (r < 24704) {                // layer0 M0 rows
            int i = r - 24576;
            const float4* row = (const float4*)(ws + OFF_M0 + (size_t)i * D0);
            if (lane < 32) { float4 a = row[lane], b = xv0[lane];
                p = a.x*b.x + a.y*b.y + a.z*b.z + a.w*b.w; }
            p = waveReduceSum(p);
            if (lane == 0) atomicAdd(&aax0[i], p);
        } else if (r < 25216) {                // u2 = Wu1 @ x1
            int i = r - 24704;
            const float4* row = (const float4*)(Wu1 + (size_t)i * D1);
            float4 a = row[lane], b = xv1[lane];
            p = a.x*b.x + a.y*b.y + a.z*b.z + a.w*b.w;
            p = waveReduceSum(p);
            if (lane == 0) { atomicAdd(&u2a[i], p); out[OU2 + (size_t)t * D2 + i] = p; }
        } else {                               // u1 = Wu0 @ x0
            int i = r - 25216;
            const float4* row = (const float4*)(Wu0 + (size_t)i * D0);
            if (lane < 32) { float4 a = row[lane], b = xv0[lane];
                p = a.x*b.x + a.y*b.y + a.z*b.z + a.w*b.w; }
            p = waveReduceSum(p);
            if (lane == 0) { atomicAdd(&u1a[i], p); out[OU1 + (size_t)t * D1 + i] = p; }
        }
    }

    // device-release then count arrivals; last block finalizes the step
    __threadfence();
    __syncthreads();
    __shared__ int lastFlag;
    if (tid == 0) {
        int* ctr = (int*)(ws + OFF_CTR);
        lastFlag = (atomicAdd(&ctr[t], 1) == NBLK - 1);
    }
    __syncthreads();
    if (!lastFlag) return;
    __threadfence();   // device-acquire: all other blocks' atomics now visible

    __shared__ float sx0n[D0], sx1n[D1], sx2n[D2], spre[64], spa[3];
    float g0 = gam[0], g1 = gam[1], g2 = gam[2];

    for (int i = tid; i < D2; i += NTHR) {
        float x = s2[i];
        float xn = x + ((1.f - g2) * aax2[i] - g2 * x + u2a[i]) * DTTAU;
        sx2n[i] = xn; (ws + OFF_S2)[(size_t)(t + 1) * D2 + i] = xn;
        out[OX2 + (size_t)t * D2 + i] = xn;
    }
    for (int i = tid; i < D1; i += NTHR) {
        float x = s1[i];
        float xn = x + ((1.f - g1) * aax1[i] - g1 * x + u1a[i]) * DTTAU;
        sx1n[i] = xn; (ws + OFF_S1)[(size_t)(t + 1) * D1 + i] = xn;
        out[OX1 + (size_t)t * D1 + i] = xn;
    }
    if (tid < D0) {
        float x = s0[tid];
        float xn = x + ((1.f - g0) * aax0[tid] - g0 * x) * DTTAU;
        sx0n[tid] = xn; (ws + OFF_S0)[(size_t)(t + 1) * D0 + tid] = xn;
        out[OX0 + (size_t)t * D0 + tid] = xn;
    }
    __syncthreads();

    // alpha(t+1) pre-activations: 8 lanes per row, 2 rows per group
    if (t < T_STEPS - 1) {
        int g = tid >> 3, sub = tid & 7;
        float p1 = 0.f;
        for (int j = sub; j < D0; j += 8) p1 += Wa0[g * D0 + j] * sx0n[j];
        p1 += __shfl_xor(p1, 4, 64); p1 += __shfl_xor(p1, 2, 64); p1 += __shfl_xor(p1, 1, 64);
        float p2 = 0.f;
        for (int j = sub; j < D1; j += 8) p2 += Wa1[g * D1 + j] * sx1n[j];
        p2 += __shfl_xor(p2, 4, 64); p2 += __shfl_xor(p2, 2, 64); p2 += __shfl_xor(p2, 1, 64);
        if (sub == 0) { spre[g] = p1 + ba0[g]; spre[32 + g] = p2 + ba1[g]; }
    }
    __syncthreads();

    int wv2 = tid >> 6;
    if (wv2 == 0 && t < T_STEPS - 1) {
        // half-wave softmaxes: lanes 0-31 -> alpha1, lanes 32-63 -> alpha2
        float v = spre[lane];
        float m = v;
        for (int msk = 16; msk >= 1; msk >>= 1) m = fmaxf(m, __shfl_xor(m, msk, 64));
        float e = expf(v - m);
        float ssum = e;
        for (int msk = 16; msk >= 1; msk >>= 1) ssum += __shfl_xor(ssum, msk, 64);
        float al = e / ssum;
        if (lane < 32) { (ws + OFF_AL1)[(size_t)(t + 1) * KK + lane] = al;
                         out[OA1 + (size_t)(t + 1) * KK + lane] = al; }
        else           { (ws + OFF_AL2)[(size_t)(t + 1) * KK + (lane - 32)] = al;
                         out[OA2 + (size_t)(t + 1) * KK + (lane - 32)] = al; }
    } else if (wv2 >= 1 && wv2 <= 3) {
        // pen_actions = Wp @ x2_new + bp  (one wave per row)
        int rr = wv2 - 1;
        float pp = 0.f;
        for (int j = lane; j < D2; j += 64) pp += Wp[rr * D2 + j] * sx2n[j];
        pp = waveReduceSum(pp);
        if (lane == 0) spa[rr] = pp + bp[rr];
    }
    __syncthreads();

    if (tid == 0) {
        float dy = spa[0], dx = spa[1], z = spa[2];
        float pdlp = fminf(z, 0.f) - log1pf(expf(-fabsf(z)));
        float* pens = ws + OFF_PENS;
        float piny = pens[0], pinx = pens[1];
        float* pxyp = ws + OFF_PXYP + (size_t)t * 3;
        pxyp[0] = piny; pxyp[1] = pinx; pxyp[2] = pdlp;   // p_xy uses pen BEFORE update
        float py = piny + dy, px = pinx + dx;
        py = 105.f / (1.f + expf(-(py - 52.5f) * (4.f / 105.f)));
        px = 105.f / (1.f + expf(-(px - 52.5f) * (4.f / 105.f)));
        pens[0] = py; pens[1] = px;
        out[OPEN + (size_t)t * 2] = py;
        out[OPEN + (size_t)t * 2 + 1] = px;
        out[OPDLP + t] = pdlp;
    }
}

// ---------------- p_xy image: fully parallel once pen trajectory is known ----------------
__global__ __launch_bounds__(NTHR) void pxy_kernel(
    const float* __restrict__ plv, const float* __restrict__ ws, float* __restrict__ out)
{
    int t = blockIdx.x;
    const float* pxyp = ws + OFF_PXYP + (size_t)t * 3;
    float py = pxyp[0], px = pxyp[1], pdlp = pxyp[2];
    float inv_var = 1.0f / (expf(plv[0]) + 1e-16f);
    for (int p = threadIdx.x; p < NPIX; p += NTHR) {
        int i = p / IMGW, j = p % IMGW;
        float ddy = py - ((float)i + 0.5f);
        float ddx = px - ((float)j + 0.5f);
        float v = expf(-0.5f * inv_var * (ddy * ddy + ddx * ddx) + pdlp);
        out[OPXY + (size_t)t * NPIX + p] = v + 1e-16f;
    }
}

extern "C" void kernel_launch(void* const* d_in, const int* in_sizes, int n_in,
                              void* d_out, int out_size, void* d_ws, size_t ws_size,
                              hipStream_t stream)
{
    const void*  data = d_in[0];
    const float* z1  = (const float*)d_in[1];
    const float* z2  = (const float*)d_in[2];
    const float* gam = (const float*)d_in[3];
    const float* plv = (const float*)d_in[4];
    const float* Wa0 = (const float*)d_in[5];
    const float* Wa1 = (const float*)d_in[6];
    const float* ba0 = (const float*)d_in[7];
    const float* ba1 = (const float*)d_in[8];
    const float* Wu0 = (const float*)d_in[9];
    const float* Wu1 = (const float*)d_in[10];
    const float* Wp  = (const float*)d_in[11];
    const float* bp  = (const float*)d_in[12];
    const float* A0  = (const float*)d_in[13];
    const float* A1  = (const float*)d_in[14];
    const float* A2  = (const float*)d_in[15];
    float* out = (float*)d_out;
    float* ws  = (float*)d_ws;

    hipLaunchKernelGGL(setup_kernel, dim3(256), dim3(NTHR), 0, stream,
                       data, z1, z2, Wa0, Wa1, ba0, ba1, ws, out);
    hipLaunchKernelGGL(m0_kernel, dim3(64), dim3(NTHR), 0, stream, z1, A0, ws);
    hipLaunchKernelGGL(fill_kernel, dim3(128), dim3(NTHR), 0, stream, z1, out);
    for (int t = 0; t < T_STEPS; t++) {
        hipLaunchKernelGGL(step_kernel, dim3(NBLK), dim3(NTHR), 0, stream, t,
                           A1, A2, Wu0, Wu1, Wa0, Wa1, ba0, ba1, Wp, bp, gam, ws, out);
    }
    hipLaunchKernelGGL(pxy_kernel, dim3(T_STEPS), dim3(NTHR), 0, stream, plv, ws, out);
}

// Round 3
// 10376.762 us; speedup vs baseline: 6.8399x; 6.8399x over previous
//
#include <hip/hip_runtime.h>
#include <math.h>

#define T_STEPS 1000
#define KK 32
#define D0 128
#define D1 256
#define D2 512
#define IMGH 105
#define IMGW 105
#define NPIX (IMGH*IMGW)
#define DTTAU 0.01f

// ---- workspace float offsets ----
#define OFF_M0   0          // 128*128
#define OFF_S0   16384      // 1001*128 states (S[t] = state at START of step t)
#define OFF_S1   144512     // 1001*256
#define OFF_S2   400768     // 1001*512
#define OFF_PA   913280     // 1000*3 pen_actions (pre-bias-activation results + bias)
#define OFF_PXYP 916280     // 1000*3 (pen_in_y, pen_in_x, pdlp)
#define OFF_PENS 919280     // 2 pen state

// ---- output float offsets (reference return order, each stacked over T) ----
#define OA0  0          // (1000,32)  alphas[0] = z1 broadcast
#define OA1  32000      // (1000,32)
#define OA2  64000      // (1000,32)
#define OU0  96000      // (1000,128) zeros
#define OU1  224000     // (1000,256)
#define OU2  480000     // (1000,512)
#define OX0  992000     // (1000,128)
#define OX1  1120000    // (1000,256)
#define OX2  1376000    // (1000,512)
#define OPEN 1888000    // (1000,2)
#define OPXY 1890000    // (1000,105,105)
#define OPDLP 12915000  // (1000,)

#define NTHR 256
// step grid: 256 L2-blocks | 128 L1-blocks | 32 L0-blocks
#define NBLK_STEP 416

#define DOT4(a,b) ((a).x*(b).x + (a).y*(b).y + (a).z*(b).z + (a).w*(b).w)

__device__ __forceinline__ float waveReduceSum(float v) {
    for (int m = 32; m >= 1; m >>= 1) v += __shfl_xor(v, m, 64);
    return v;
}

// ---------------- setup: init states, pen0 ----------------
__global__ __launch_bounds__(NTHR) void setup_kernel(
    const void* __restrict__ dataRaw, const float* __restrict__ z2,
    float* __restrict__ ws)
{
    if (blockIdx.x != 0) return;
    int tid = threadIdx.x;

    // initial states: x0 = z2, x1 = 0, x2 = 0
    if (tid < D0) (ws + OFF_S0)[tid] = z2[tid];
    for (int i = tid; i < D1; i += NTHR) (ws + OFF_S1)[i] = 0.f;
    for (int i = tid; i < D2; i += NTHR) (ws + OFF_S2)[i] = 0.f;

    // pen0 = argwhere(data)[0]; robust to bool stored as uint8 or int32
    __shared__ int sMin;
    if (tid == 0) sMin = 0x7fffffff;
    __syncthreads();
    const unsigned char* db = (const unsigned char*)dataRaw;
    for (int i = tid; i < NPIX; i += NTHR) if (db[i]) atomicMin(&sMin, i);
    __syncthreads();
    if (sMin == 0x7fffffff) {
        const int* di = (const int*)dataRaw;
        for (int i = tid; i < NPIX; i += NTHR) if (di[i] != 0) atomicMin(&sMin, i);
    }
    __syncthreads();
    if (tid == 0) {
        int idx = (sMin == 0x7fffffff) ? 0 : sMin;
        (ws + OFF_PENS)[0] = (float)(idx / IMGW);
        (ws + OFF_PENS)[1] = (float)(idx % IMGW);
    }
}

// ---------------- M0 = sum_k z1[k] * A0[k] ----------------
__global__ __launch_bounds__(NTHR) void m0_kernel(
    const float* __restrict__ z1, const float* __restrict__ A0, float* __restrict__ ws)
{
    int idx = blockIdx.x * NTHR + threadIdx.x;
    if (idx < D0 * D0) {
        float s = 0.f;
        for (int k = 0; k < KK; k++) s += z1[k] * A0[(size_t)k * D0 * D0 + idx];
        ws[OFF_M0 + idx] = s;
    }
}

// ---------------- trivial outputs: alpha0 broadcast, u0 zeros ----------------
__global__ __launch_bounds__(NTHR) void fill_kernel(const float* __restrict__ z1, float* __restrict__ out)
{
    size_t gid = (size_t)blockIdx.x * blockDim.x + threadIdx.x;
    size_t nthr = (size_t)gridDim.x * blockDim.x;
    for (size_t i = gid; i < 32000; i += nthr) out[OA0 + i] = z1[i & 31];
    for (size_t i = gid; i < 128000; i += nthr) out[OU0 + i] = 0.f;
}

// ---------------- one recurrence step: join-free (no atomics, no fences) ----------------
// blocks 0..255   : layer2, 2 elements each, k split across wave pairs (16 k per wave)
// blocks 256..383 : layer1, 2 elements each, same pattern
// blocks 384..415 : layer0, 4 elements each, 1 wave per element (M0 precombined)
__global__ __launch_bounds__(NTHR) void step_kernel(
    int t,
    const float* __restrict__ A1, const float* __restrict__ A2,
    const float* __restrict__ Wu0, const float* __restrict__ Wu1,
    const float* __restrict__ Wa0, const float* __restrict__ Wa1,
    const float* __restrict__ ba0, const float* __restrict__ ba1,
    const float* __restrict__ gam,
    float* __restrict__ ws, float* __restrict__ out)
{
    const int tid = threadIdx.x;
    const int lane = tid & 63;
    const int w = tid >> 6;
    const int b = blockIdx.x;

    const float* s0 = ws + OFF_S0 + (size_t)t * D0;
    const float* s1 = ws + OFF_S1 + (size_t)t * D1;
    const float* s2 = ws + OFF_S2 + (size_t)t * D2;
    float* s0n = ws + OFF_S0 + (size_t)(t + 1) * D0;
    float* s1n = ws + OFF_S1 + (size_t)(t + 1) * D1;
    float* s2n = ws + OFF_S2 + (size_t)(t + 1) * D2;
    const float4* xv0 = (const float4*)s0;
    const float4* xv1 = (const float4*)s1;
    const float4* xv2 = (const float4*)s2;

    __shared__ float sAl[KK];
    __shared__ float sPre[KK];
    __shared__ float sPart[4];
    __shared__ float sU[2];

    if (b < 256) {
        // ======== layer 2 ========
        // alpha2 = softmax(Wa1 @ x1 + ba1), computed per block
        {
            int g = tid >> 3, sub = tid & 7;
            const float4* wr = (const float4*)(Wa1 + (size_t)g * D1);
            float pr = 0.f;
            #pragma unroll
            for (int it = 0; it < 8; ++it) {
                float4 a = wr[sub + 8 * it], x = xv1[sub + 8 * it];
                pr += DOT4(a, x);
            }
            pr += __shfl_xor(pr, 4, 64); pr += __shfl_xor(pr, 2, 64); pr += __shfl_xor(pr, 1, 64);
            if (sub == 0) sPre[g] = pr + ba1[g];
        }
        __syncthreads();
        if (tid < 32) {
            float v = sPre[tid];
            float m = v;
            for (int msk = 16; msk >= 1; msk >>= 1) m = fmaxf(m, __shfl_xor(m, msk, 32));
            float e = expf(v - m);
            float ssum = e;
            for (int msk = 16; msk >= 1; msk >>= 1) ssum += __shfl_xor(ssum, msk, 32);
            float al = e / ssum;
            sAl[tid] = al;
            if (b == 0) out[OA2 + (size_t)t * KK + tid] = al;
        }
        __syncthreads();

        int elem = 2 * b + (w >> 1);
        int k0 = (w & 1) * 16;
        float4 xa = xv2[lane], xb = xv2[64 + lane];
        float acc = 0.f;
        #pragma unroll 4
        for (int kk = 0; kk < 16; ++kk) {
            int k = k0 + kk;
            const float4* row = (const float4*)(A2 + ((size_t)(k * D2 + elem)) * D2);
            float4 a0 = row[lane], a1 = row[64 + lane];
            acc += sAl[k] * (DOT4(a0, xa) + DOT4(a1, xb));
        }
        acc = waveReduceSum(acc);
        float ures = 0.f;
        if ((w & 1) == 0) {
            const float4* wrow = (const float4*)(Wu1 + (size_t)elem * D1);
            float4 ww = wrow[lane], xx = xv1[lane];
            ures = DOT4(ww, xx);
            ures = waveReduceSum(ures);
        }
        if (lane == 0) { sPart[w] = acc; if ((w & 1) == 0) sU[w >> 1] = ures; }
        __syncthreads();
        if (tid < 2) {
            int e2 = 2 * b + tid;
            float aax = sPart[2 * tid] + sPart[2 * tid + 1];
            float u = sU[tid];
            float gv = gam[2];
            float x = s2[e2];
            float xn = x + ((1.f - gv) * aax - gv * x + u) * DTTAU;
            s2n[e2] = xn;
            out[OX2 + (size_t)t * D2 + e2] = xn;
            out[OU2 + (size_t)t * D2 + e2] = u;
        }
    } else if (b < 384) {
        // ======== layer 1 ========
        // alpha1 = softmax(Wa0 @ x0 + ba0)
        {
            int g = tid >> 3, sub = tid & 7;
            const float4* wr = (const float4*)(Wa0 + (size_t)g * D0);
            float pr = 0.f;
            #pragma unroll
            for (int it = 0; it < 4; ++it) {
                float4 a = wr[sub + 8 * it], x = xv0[sub + 8 * it];
                pr += DOT4(a, x);
            }
            pr += __shfl_xor(pr, 4, 64); pr += __shfl_xor(pr, 2, 64); pr += __shfl_xor(pr, 1, 64);
            if (sub == 0) sPre[g] = pr + ba0[g];
        }
        __syncthreads();
        if (tid < 32) {
            float v = sPre[tid];
            float m = v;
            for (int msk = 16; msk >= 1; msk >>= 1) m = fmaxf(m, __shfl_xor(m, msk, 32));
            float e = expf(v - m);
            float ssum = e;
            for (int msk = 16; msk >= 1; msk >>= 1) ssum += __shfl_xor(ssum, msk, 32);
            float al = e / ssum;
            sAl[tid] = al;
            if (b == 256) out[OA1 + (size_t)t * KK + tid] = al;
        }
        __syncthreads();

        int bb = b - 256;
        int elem = 2 * bb + (w >> 1);
        int k0 = (w & 1) * 16;
        float4 xc = xv1[lane];
        float acc = 0.f;
        #pragma unroll 4
        for (int kk = 0; kk < 16; ++kk) {
            int k = k0 + kk;
            const float4* row = (const float4*)(A1 + ((size_t)(k * D1 + elem)) * D1);
            float4 a = row[lane];
            acc += sAl[k] * DOT4(a, xc);
        }
        acc = waveReduceSum(acc);
        float ures = 0.f;
        if ((w & 1) == 0) {
            if (lane < 32) {
                const float4* wrow = (const float4*)(Wu0 + (size_t)elem * D0);
                float4 ww = wrow[lane], xx = xv0[lane];
                ures = DOT4(ww, xx);
            }
            ures = waveReduceSum(ures);
        }
        if (lane == 0) { sPart[w] = acc; if ((w & 1) == 0) sU[w >> 1] = ures; }
        __syncthreads();
        if (tid < 2) {
            int e2 = 2 * bb + tid;
            float aax = sPart[2 * tid] + sPart[2 * tid + 1];
            float u = sU[tid];
            float gv = gam[1];
            float x = s1[e2];
            float xn = x + ((1.f - gv) * aax - gv * x + u) * DTTAU;
            s1n[e2] = xn;
            out[OX1 + (size_t)t * D1 + e2] = xn;
            out[OU1 + (size_t)t * D1 + e2] = u;
        }
    } else {
        // ======== layer 0 (M0 already z1-combined; u0 = 0) ========
        int bb = b - 384;
        int elem = 4 * bb + w;
        float d = 0.f;
        if (lane < 32) {
            const float4* row = (const float4*)(ws + OFF_M0 + (size_t)elem * D0);
            float4 a = row[lane], x = xv0[lane];
            d = DOT4(a, x);
        }
        d = waveReduceSum(d);
        if (lane == 0) {
            float gv = gam[0];
            float x = s0[elem];
            float xn = x + ((1.f - gv) * d - gv * x) * DTTAU;
            s0n[elem] = xn;
            out[OX0 + (size_t)t * D0 + elem] = xn;
        }
    }
}

// ---------------- pen_actions for all t in parallel: pa[t,r] = Wp[r]@x2(t+1) + bp[r] ----------------
__global__ __launch_bounds__(192) void pa_kernel(
    const float* __restrict__ Wp, const float* __restrict__ bp, float* __restrict__ ws)
{
    int t = blockIdx.x;
    int w = threadIdx.x >> 6, lane = threadIdx.x & 63;
    const float4* x2 = (const float4*)(ws + OFF_S2 + (size_t)(t + 1) * D2);
    const float4* wr = (const float4*)(Wp + (size_t)w * D2);
    float p = 0.f;
    #pragma unroll
    for (int it = 0; it < 2; ++it) {
        float4 a = wr[lane + 64 * it], x = x2[lane + 64 * it];
        p += DOT4(a, x);
    }
    p = waveReduceSum(p);
    if (lane == 0) ws[OFF_PA + (size_t)t * 3 + w] = p + bp[w];
}

// ---------------- scalar pen recurrence over T (inherently serial, tiny) ----------------
__global__ void chain_kernel(float* __restrict__ ws, float* __restrict__ out)
{
    if (blockIdx.x != 0 || threadIdx.x != 0) return;
    float py = ws[OFF_PENS], px = ws[OFF_PENS + 1];
    for (int t = 0; t < T_STEPS; ++t) {
        float dy = ws[OFF_PA + t * 3], dx = ws[OFF_PA + t * 3 + 1], z = ws[OFF_PA + t * 3 + 2];
        float pdlp = fminf(z, 0.f) - log1pf(expf(-fabsf(z)));
        ws[OFF_PXYP + t * 3] = py; ws[OFF_PXYP + t * 3 + 1] = px; ws[OFF_PXYP + t * 3 + 2] = pdlp;
        float ny = py + dy, nx = px + dx;
        ny = 105.f / (1.f + expf(-(ny - 52.5f) * (4.f / 105.f)));
        nx = 105.f / (1.f + expf(-(nx - 52.5f) * (4.f / 105.f)));
        py = ny; px = nx;
        out[OPEN + (size_t)t * 2] = py;
        out[OPEN + (size_t)t * 2 + 1] = px;
        out[OPDLP + t] = pdlp;
    }
}

// ---------------- p_xy image: fully parallel once pen trajectory is known ----------------
__global__ __launch_bounds__(NTHR) void pxy_kernel(
    const float* __restrict__ plv, const float* __restrict__ ws, float* __restrict__ out)
{
    int t = blockIdx.x;
    const float* pxyp = ws + OFF_PXYP + (size_t)t * 3;
    float py = pxyp[0], px = pxyp[1], pdlp = pxyp[2];
    float inv_var = 1.0f / (expf(plv[0]) + 1e-16f);
    for (int p = threadIdx.x; p < NPIX; p += NTHR) {
        int i = p / IMGW, j = p % IMGW;
        float ddy = py - ((float)i + 0.5f);
        float ddx = px - ((float)j + 0.5f);
        float v = expf(-0.5f * inv_var * (ddy * ddy + ddx * ddx) + pdlp);
        out[OPXY + (size_t)t * NPIX + p] = v + 1e-16f;
    }
}

extern "C" void kernel_launch(void* const* d_in, const int* in_sizes, int n_in,
                              void* d_out, int out_size, void* d_ws, size_t ws_size,
                              hipStream_t stream)
{
    const void*  data = d_in[0];
    const float* z1  = (const float*)d_in[1];
    const float* z2  = (const float*)d_in[2];
    const float* gam = (const float*)d_in[3];
    const float* plv = (const float*)d_in[4];
    const float* Wa0 = (const float*)d_in[5];
    const float* Wa1 = (const float*)d_in[6];
    const float* ba0 = (const float*)d_in[7];
    const float* ba1 = (const float*)d_in[8];
    const float* Wu0 = (const float*)d_in[9];
    const float* Wu1 = (const float*)d_in[10];
    const float* Wp  = (const float*)d_in[11];
    const float* bp  = (const float*)d_in[12];
    const float* A0  = (const float*)d_in[13];
    const float* A1  = (const float*)d_in[14];
    const float* A2  = (const float*)d_in[15];
    float* out = (float*)d_out;
    float* ws  = (float*)d_ws;

    hipLaunchKernelGGL(setup_kernel, dim3(1), dim3(NTHR), 0, stream, data, z2, ws);
    hipLaunchKernelGGL(m0_kernel, dim3(64), dim3(NTHR), 0, stream, z1, A0, ws);
    hipLaunchKernelGGL(fill_kernel, dim3(128), dim3(NTHR), 0, stream, z1, out);
    for (int t = 0; t < T_STEPS; t++) {
        hipLaunchKernelGGL(step_kernel, dim3(NBLK_STEP), dim3(NTHR), 0, stream, t,
                           A1, A2, Wu0, Wu1, Wa0, Wa1, ba0, ba1, gam, ws, out);
    }
    hipLaunchKernelGGL(pa_kernel, dim3(T_STEPS), dim3(192), 0, stream, Wp, bp, ws);
    hipLaunchKernelGGL(chain_kernel, dim3(1), dim3(64), 0, stream, ws, out);
    hipLaunchKernelGGL(pxy_kernel, dim3(T_STEPS), dim3(NTHR), 0, stream, plv, ws, out);
}